// Round 1
// baseline (1608.845 us; speedup 1.0000x reference)
//
#include <hip/hip_runtime.h>
#include <hip/hip_bf16.h>

#define M_DIM 8192      // B*S = 4*2048
#define K_DIM 4096
#define N_DIM 16384

#define BM 128
#define BN 128
#define BK 64

typedef __attribute__((ext_vector_type(8))) short bf16x8;
typedef __attribute__((ext_vector_type(4))) float f32x4;
typedef __attribute__((ext_vector_type(4))) unsigned short u16x4;

__device__ __forceinline__ unsigned short f2bf(float f) {
  unsigned int u = __builtin_bit_cast(unsigned int, f);
  u += 0x7fffu + ((u >> 16) & 1u);     // RNE
  return (unsigned short)(u >> 16);
}

// fp32 -> bf16, 4 elements/thread/iter, grid-stride
__global__ void cvt_kernel(const float* __restrict__ src,
                           unsigned short* __restrict__ dst, int n4) {
  int i = blockIdx.x * blockDim.x + threadIdx.x;
  int stride = gridDim.x * blockDim.x;
  for (; i < n4; i += stride) {
    f32x4 v = ((const f32x4*)src)[i];
    u16x4 o;
    o.x = f2bf(v.x); o.y = f2bf(v.y); o.z = f2bf(v.z); o.w = f2bf(v.w);
    ((u16x4*)dst)[i] = o;
  }
}

__device__ __forceinline__ void gload_lds16(const void* g, void* lds) {
  __builtin_amdgcn_global_load_lds(
      (const __attribute__((address_space(1))) unsigned int*)g,
      (__attribute__((address_space(3))) unsigned int*)lds, 16, 0, 0);
}

__device__ __forceinline__ bf16x8 cvt8(f32x4 a, f32x4 b) {
  bf16x8 r;
#pragma unroll
  for (int j = 0; j < 4; ++j) {
    r[j]     = (short)f2bf(a[j]);
    r[j + 4] = (short)f2bf(b[j]);
  }
  return r;
}

// C[M][N] = A[M][K] * B[N][K]^T + bias.
// F32IN=false: A,B are bf16 (from workspace), staged via global_load_lds w=16
//              with inverse-swizzled global source (rule #21).
// F32IN=true : A,B are fp32, reg-staged + cvt, ds_write to swizzled offset.
// LDS swizzle: physical elem off within a 64-elem row = logical ^ ((row&7)<<3)
// -> ds_read_b128 fragment reads drop from 16-way to 2-way (free) conflicts.
template <bool F32IN>
__global__ __launch_bounds__(256) void gemm_k(const void* __restrict__ Av,
                                              const void* __restrict__ Bv,
                                              const float* __restrict__ bias,
                                              float* __restrict__ C) {
  __shared__ short lA[BM * BK];
  __shared__ short lB[BN * BK];

  const int tid = threadIdx.x;
  const int w = tid >> 6;          // wave 0..3
  const int l = tid & 63;          // lane
  const int wr = w >> 1, wc = w & 1;

  // XCD-aware bijective swizzle (gridDim.x = 8192, %8 == 0)
  int bid = blockIdx.x;
  int swz = bid;
  if ((gridDim.x & 7) == 0) {
    int cpx = gridDim.x >> 3;
    swz = (bid & 7) * cpx + (bid >> 3);
  }
  const int bm = swz / (N_DIM / BN);
  const int bn = swz % (N_DIM / BN);
  const size_t m0 = (size_t)bm * BM;
  const size_t n0 = (size_t)bn * BN;

  const int lr = l >> 3;               // staging row-within-8
  const int lcs = (l & 7) ^ lr;        // inverse-swizzled source block
  const int fr = l & 15;               // fragment row (A row / B col)
  const int kq = l >> 4;               // k quarter 0..3

  f32x4 acc[4][4];
#pragma unroll
  for (int mi = 0; mi < 4; ++mi)
#pragma unroll
    for (int ni = 0; ni < 4; ++ni) acc[mi][ni] = (f32x4){0.f, 0.f, 0.f, 0.f};

  float bv[4];
#pragma unroll
  for (int ni = 0; ni < 4; ++ni) bv[ni] = bias[n0 + 64 * wc + 16 * ni + fr];

  for (int kt = 0; kt < K_DIM; kt += BK) {
    if constexpr (!F32IN) {
      const short* Ab = (const short*)Av + m0 * K_DIM + kt;
      const short* Bb = (const short*)Bv + n0 * K_DIM + kt;
#pragma unroll
      for (int i = 0; i < 4; ++i) {
        int row = 32 * i + 8 * w + lr;
        gload_lds16(Ab + (size_t)row * K_DIM + 8 * lcs, &lA[(32 * i + 8 * w) * BK]);
        gload_lds16(Bb + (size_t)row * K_DIM + 8 * lcs, &lB[(32 * i + 8 * w) * BK]);
      }
    } else {
      const float* Af = (const float*)Av + m0 * K_DIM + kt;
      const float* Bf = (const float*)Bv + n0 * K_DIM + kt;
#pragma unroll
      for (int i = 0; i < 4; ++i) {
        int row = 32 * i + 8 * w + lr;
        int dsoff = row * BK + ((8 * (l & 7)) ^ (lr << 3));
        f32x4 a0 = *(const f32x4*)(Af + (size_t)row * K_DIM + 8 * (l & 7));
        f32x4 a1 = *(const f32x4*)(Af + (size_t)row * K_DIM + 8 * (l & 7) + 4);
        *(bf16x8*)&lA[dsoff] = cvt8(a0, a1);
        f32x4 b0 = *(const f32x4*)(Bf + (size_t)row * K_DIM + 8 * (l & 7));
        f32x4 b1 = *(const f32x4*)(Bf + (size_t)row * K_DIM + 8 * (l & 7) + 4);
        *(bf16x8*)&lB[dsoff] = cvt8(b0, b1);
      }
    }
    __syncthreads();

#pragma unroll
    for (int kk = 0; kk < BK; kk += 32) {
      bf16x8 af[4], bf_[4];
#pragma unroll
      for (int mi = 0; mi < 4; ++mi)
        af[mi] = *(const bf16x8*)&lA[(64 * wr + 16 * mi + fr) * BK +
                                     ((kk + 8 * kq) ^ ((fr & 7) << 3))];
#pragma unroll
      for (int ni = 0; ni < 4; ++ni)
        bf_[ni] = *(const bf16x8*)&lB[(64 * wc + 16 * ni + fr) * BK +
                                      ((kk + 8 * kq) ^ ((fr & 7) << 3))];
#pragma unroll
      for (int mi = 0; mi < 4; ++mi)
#pragma unroll
        for (int ni = 0; ni < 4; ++ni)
          acc[mi][ni] = __builtin_amdgcn_mfma_f32_16x16x32_bf16(
              af[mi], bf_[ni], acc[mi][ni], 0, 0, 0);
    }
    __syncthreads();
  }

  // epilogue: C/D layout col = lane&15, row = (lane>>4)*4 + reg  [m89]
  const int crow0 = (l >> 4) * 4;
#pragma unroll
  for (int mi = 0; mi < 4; ++mi) {
#pragma unroll
    for (int ni = 0; ni < 4; ++ni) {
      f32x4 v = acc[mi][ni];
      size_t col = n0 + 64 * wc + 16 * ni + fr;
      size_t rb = m0 + 64 * wr + 16 * mi + crow0;
#pragma unroll
      for (int j = 0; j < 4; ++j) C[(rb + j) * N_DIM + col] = v[j] + bv[ni];
    }
  }
}

extern "C" void kernel_launch(void* const* d_in, const int* in_sizes, int n_in,
                              void* d_out, int out_size, void* d_ws, size_t ws_size,
                              hipStream_t stream) {
  const float* x = (const float*)d_in[0];     // [8192][4096]
  const float* W = (const float*)d_in[1];     // [16384][4096]
  const float* bias = (const float*)d_in[2];  // [16384]
  float* out = (float*)d_out;

  const size_t nA = (size_t)M_DIM * K_DIM;  // 33.5M
  const size_t nB = (size_t)N_DIM * K_DIM;  // 67.1M
  const size_t need = (nA + nB) * sizeof(unsigned short);  // 192 MB

  const int nblk = (M_DIM / BM) * (N_DIM / BN);  // 8192

  if (ws_size >= need) {
    unsigned short* wsA = (unsigned short*)d_ws;
    unsigned short* wsB = wsA + nA;
    cvt_kernel<<<4096, 256, 0, stream>>>(x, wsA, (int)(nA / 4));
    cvt_kernel<<<4096, 256, 0, stream>>>(W, wsB, (int)(nB / 4));
    gemm_k<false><<<nblk, 256, 0, stream>>>((const void*)wsA, (const void*)wsB,
                                            bias, out);
  } else {
    gemm_k<true><<<nblk, 256, 0, stream>>>((const void*)x, (const void*)W,
                                           bias, out);
  }
}

// Round 2
// 1074.536 us; speedup vs baseline: 1.4972x; 1.4972x over previous
//
#include <hip/hip_runtime.h>
#include <hip/hip_bf16.h>

#define M_DIM 8192      // B*S = 4*2048
#define K_DIM 4096
#define N_DIM 16384

#define BK 64
#define NT (K_DIM / BK)   // 64 K-tiles

typedef __attribute__((ext_vector_type(8))) short bf16x8;
typedef __attribute__((ext_vector_type(4))) float f32x4;
typedef __attribute__((ext_vector_type(4))) unsigned short u16x4;

__device__ __forceinline__ unsigned short f2bf(float f) {
  unsigned int u = __builtin_bit_cast(unsigned int, f);
  u += 0x7fffu + ((u >> 16) & 1u);     // RNE
  return (unsigned short)(u >> 16);
}

// fp32 -> bf16, 4 elements/thread/iter, grid-stride
__global__ void cvt_kernel(const float* __restrict__ src,
                           unsigned short* __restrict__ dst, int n4) {
  int i = blockIdx.x * blockDim.x + threadIdx.x;
  int stride = gridDim.x * blockDim.x;
  for (; i < n4; i += stride) {
    f32x4 v = ((const f32x4*)src)[i];
    u16x4 o;
    o.x = f2bf(v.x); o.y = f2bf(v.y); o.z = f2bf(v.z); o.w = f2bf(v.w);
    ((u16x4*)dst)[i] = o;
  }
}

__device__ __forceinline__ void gload_lds16(const void* g, void* lds) {
  __builtin_amdgcn_global_load_lds(
      (const __attribute__((address_space(1))) unsigned int*)g,
      (__attribute__((address_space(3))) unsigned int*)lds, 16, 0, 0);
}

// ============================================================================
// 256x256 tile, BK=64, 8 waves (2M x 4N), 8-phase schedule w/ counted vmcnt.
// LDS (128 KiB dynamic): lA = 4 slots [par][half] of 128x64 bf16 (16 KiB),
//                        lB = same at +64 KiB.
// Swizzle: phys 8-elem block = logical block ^ (row & 7)  (16B granularity).
// Staged with linear LDS dest + inverse-swizzled GLOBAL source (rule #21).
// Schedule per K-tile u (4 phases):
//   p0: read B frags (8 ds_read_b128) + A m0-1 (4) | stage Ah1(u+1)
//   p1: read A m2-3                                | stage Bh0(u+2)
//   p2: read A m4-5                                | stage Bh1(u+2)
//   p3: read A m6-7                                | stage Ah0(u+2) | vmcnt(6)
// vmcnt(6) at each boundary == all but newest 3 half-tiles landed ==
// exactly tile u+1 complete. Slot lifetime: B slots die at p0 (lgkmcnt(0) +
// barrier), A slots at p3 — every stage lands in a dead or just-read slot.
// ============================================================================
__global__ __launch_bounds__(512, 2) void gemm8(const short* __restrict__ A,
                                                const short* __restrict__ Bm,
                                                const float* __restrict__ bias,
                                                float* __restrict__ C) {
  extern __shared__ short lds[];
  short* lA = lds;           // 4 * 8192 shorts
  short* lB = lds + 32768;   // 4 * 8192 shorts

  const int tid = threadIdx.x;
  const int w = tid >> 6, l = tid & 63;
  const int wr = w >> 2;     // 0..1  (M half)
  const int wc = w & 3;      // 0..3  (N quarter)
  const int fr = l & 15;     // fragment row/col
  const int kq = l >> 4;     // k quarter
  const int sr = l >> 3;     // staging row-in-8
  const int sb = (l & 7) ^ sr;  // inverse-swizzled source block

  // XCD-aware bijective swizzle (2048 blocks, %8 == 0)
  const int nwg = (M_DIM / 256) * (N_DIM / 256);  // 2048
  int bid = blockIdx.x;
  int swz = (bid & 7) * (nwg >> 3) + (bid >> 3);
  const int bm = swz / (N_DIM / 256);
  const int bn = swz % (N_DIM / 256);
  const size_t m0 = (size_t)bm * 256, n0 = (size_t)bn * 256;

  const short* Abase = A + m0 * K_DIM;
  const short* Bbase = Bm + n0 * K_DIM;

  // stage one half-tile (128 rows x 64 elems) = 2 x gload_lds16 per thread
  auto stage = [&](short* lbase, const short* gbase, int slot, int half, int v) {
    const short* src = gbase + (size_t)(half * 128 + w * 8 + sr) * K_DIM +
                       (size_t)v * BK + sb * 8;
    short* dst = lbase + slot * 8192 + w * 512;
    gload_lds16(src, dst);                          // rows 0..63 of half
    gload_lds16(src + (size_t)64 * K_DIM, dst + 4096);  // rows 64..127
  };

  f32x4 acc[8][4];
#pragma unroll
  for (int mi = 0; mi < 8; ++mi)
#pragma unroll
    for (int ni = 0; ni < 4; ++ni) acc[mi][ni] = (f32x4){0.f, 0.f, 0.f, 0.f};

  float bv[4];
#pragma unroll
  for (int ni = 0; ni < 4; ++ni) bv[ni] = bias[n0 + wc * 64 + ni * 16 + fr];

  // ---- prologue: tile 0 complete + tile 1 {Bh0, Bh1, Ah0} ----
  stage(lB, Bbase, 0, 0, 0);
  stage(lB, Bbase, 1, 1, 0);
  stage(lA, Abase, 0, 0, 0);
  stage(lA, Abase, 1, 1, 0);
  stage(lB, Bbase, 2, 0, 1);
  stage(lB, Bbase, 3, 1, 1);
  stage(lA, Abase, 2, 0, 1);
  asm volatile("s_waitcnt vmcnt(6)");   // tile 0's 4 half-tiles landed
  __builtin_amdgcn_s_barrier();
  __builtin_amdgcn_sched_barrier(0);

  // ---- one K-tile group (4 phases); par is compile-time via call sites ----
  auto group = [&](const int par, const int u) {
    bf16x8 bfr[4][2];
#pragma unroll
    for (int p = 0; p < 4; ++p) {
      if (p == 0) {
#pragma unroll
        for (int ni = 0; ni < 4; ++ni) {
          int row = (wc & 1) * 64 + ni * 16 + fr;
          int base = (par * 2 + (wc >> 1)) * 8192 + row * 64;
          int x7 = (row & 7) << 3;
          bfr[ni][0] = *(const bf16x8*)&lB[base + ((kq * 8) ^ x7)];
          bfr[ni][1] = *(const bf16x8*)&lB[base + ((32 + kq * 8) ^ x7)];
        }
      }
      bf16x8 af[2][2];
#pragma unroll
      for (int i = 0; i < 2; ++i) {
        int row = (2 * p + i) * 16 + fr;
        int base = (par * 2 + wr) * 8192 + row * 64;
        int x7 = (row & 7) << 3;
        af[i][0] = *(const bf16x8*)&lA[base + ((kq * 8) ^ x7)];
        af[i][1] = *(const bf16x8*)&lA[base + ((32 + kq * 8) ^ x7)];
      }
      // staging per schedule
      if (p == 0) { if (u + 1 < NT) stage(lA, Abase, ((u + 1) & 1) * 2 + 1, 1, u + 1); }
      if (p == 1) { if (u + 2 < NT) stage(lB, Bbase, par * 2 + 0, 0, u + 2); }
      if (p == 2) { if (u + 2 < NT) stage(lB, Bbase, par * 2 + 1, 1, u + 2); }
      if (p == 3) { if (u + 2 < NT) stage(lA, Abase, par * 2 + 0, 0, u + 2); }

      if (p == 0) asm volatile("s_waitcnt lgkmcnt(8)");
      __builtin_amdgcn_sched_barrier(0);
      __builtin_amdgcn_s_barrier();
      asm volatile("s_waitcnt lgkmcnt(0)");
      __builtin_amdgcn_sched_barrier(0);
      __builtin_amdgcn_s_setprio(1);
#pragma unroll
      for (int i = 0; i < 2; ++i)
#pragma unroll
        for (int ni = 0; ni < 4; ++ni) {
          acc[2 * p + i][ni] = __builtin_amdgcn_mfma_f32_16x16x32_bf16(
              af[i][0], bfr[ni][0], acc[2 * p + i][ni], 0, 0, 0);
          acc[2 * p + i][ni] = __builtin_amdgcn_mfma_f32_16x16x32_bf16(
              af[i][1], bfr[ni][1], acc[2 * p + i][ni], 0, 0, 0);
        }
      __builtin_amdgcn_s_setprio(0);
      if (p == 3) {
        if (u < NT - 2) {
          asm volatile("s_waitcnt vmcnt(6)");   // next tile fully landed
        } else if (u == NT - 2) {
          asm volatile("s_waitcnt vmcnt(0)");   // drain for last tile
        }
      }
      __builtin_amdgcn_sched_barrier(0);
      __builtin_amdgcn_s_barrier();
      __builtin_amdgcn_sched_barrier(0);
    }
  };

  for (int t = 0; t < NT; t += 2) {
    group(0, t);
    group(1, t + 1);
  }

  // ---- epilogue: C/D layout col = lane&15, row = (lane>>4)*4 + reg ----
  const int crow0 = kq * 4;
#pragma unroll
  for (int mi = 0; mi < 8; ++mi) {
#pragma unroll
    for (int ni = 0; ni < 4; ++ni) {
      f32x4 v = acc[mi][ni];
      size_t col = n0 + wc * 64 + ni * 16 + fr;
      size_t rb = m0 + wr * 128 + mi * 16 + crow0;
#pragma unroll
      for (int j = 0; j < 4; ++j) C[(rb + j) * N_DIM + col] = v[j] + bv[ni];
    }
  }
}

// ---- fallback (ws too small): round-1 128^2 kernel, fp32 in, reg-staged ----
__global__ __launch_bounds__(256) void gemm_f32(const float* __restrict__ Af,
                                                const float* __restrict__ Bf,
                                                const float* __restrict__ bias,
                                                float* __restrict__ C) {
  __shared__ short lA[128 * 64];
  __shared__ short lB[128 * 64];
  const int tid = threadIdx.x;
  const int w = tid >> 6, l = tid & 63;
  const int wr = w >> 1, wc = w & 1;
  int bid = blockIdx.x;
  int cpx = (M_DIM / 128) * (N_DIM / 128) / 8;
  int swz = (bid & 7) * cpx + (bid >> 3);
  const int bm = swz / (N_DIM / 128);
  const int bn = swz % (N_DIM / 128);
  const size_t m0 = (size_t)bm * 128, n0 = (size_t)bn * 128;
  const int lr = l >> 3, fr = l & 15, kq = l >> 4;

  f32x4 acc[4][4];
#pragma unroll
  for (int mi = 0; mi < 4; ++mi)
#pragma unroll
    for (int ni = 0; ni < 4; ++ni) acc[mi][ni] = (f32x4){0.f, 0.f, 0.f, 0.f};
  float bv[4];
#pragma unroll
  for (int ni = 0; ni < 4; ++ni) bv[ni] = bias[n0 + 64 * wc + 16 * ni + fr];

  for (int kt = 0; kt < K_DIM; kt += 64) {
    const float* Ab = Af + m0 * K_DIM + kt;
    const float* Bb = Bf + n0 * K_DIM + kt;
#pragma unroll
    for (int i = 0; i < 4; ++i) {
      int row = 32 * i + 8 * w + lr;
      int dsoff = row * 64 + ((8 * (l & 7)) ^ (lr << 3));
      f32x4 a0 = *(const f32x4*)(Ab + (size_t)row * K_DIM + 8 * (l & 7));
      f32x4 a1 = *(const f32x4*)(Ab + (size_t)row * K_DIM + 8 * (l & 7) + 4);
      bf16x8 ra;
#pragma unroll
      for (int j = 0; j < 4; ++j) { ra[j] = (short)f2bf(a0[j]); ra[j + 4] = (short)f2bf(a1[j]); }
      *(bf16x8*)&lA[dsoff] = ra;
      f32x4 b0 = *(const f32x4*)(Bb + (size_t)row * K_DIM + 8 * (l & 7));
      f32x4 b1 = *(const f32x4*)(Bb + (size_t)row * K_DIM + 8 * (l & 7) + 4);
      bf16x8 rb;
#pragma unroll
      for (int j = 0; j < 4; ++j) { rb[j] = (short)f2bf(b0[j]); rb[j + 4] = (short)f2bf(b1[j]); }
      *(bf16x8*)&lB[dsoff] = rb;
    }
    __syncthreads();
#pragma unroll
    for (int kk = 0; kk < 64; kk += 32) {
      bf16x8 af[4], bf_[4];
#pragma unroll
      for (int mi = 0; mi < 4; ++mi)
        af[mi] = *(const bf16x8*)&lA[(64 * wr + 16 * mi + fr) * 64 +
                                     ((kk + 8 * kq) ^ ((fr & 7) << 3))];
#pragma unroll
      for (int ni = 0; ni < 4; ++ni)
        bf_[ni] = *(const bf16x8*)&lB[(64 * wc + 16 * ni + fr) * 64 +
                                      ((kk + 8 * kq) ^ ((fr & 7) << 3))];
#pragma unroll
      for (int mi = 0; mi < 4; ++mi)
#pragma unroll
        for (int ni = 0; ni < 4; ++ni)
          acc[mi][ni] = __builtin_amdgcn_mfma_f32_16x16x32_bf16(
              af[mi], bf_[ni], acc[mi][ni], 0, 0, 0);
    }
    __syncthreads();
  }
  const int crow0 = kq * 4;
#pragma unroll
  for (int mi = 0; mi < 4; ++mi)
#pragma unroll
    for (int ni = 0; ni < 4; ++ni) {
      f32x4 v = acc[mi][ni];
      size_t col = n0 + 64 * wc + 16 * ni + fr;
      size_t rb = m0 + 64 * wr + 16 * mi + crow0;
#pragma unroll
      for (int j = 0; j < 4; ++j) C[(rb + j) * N_DIM + col] = v[j] + bv[ni];
    }
}

extern "C" void kernel_launch(void* const* d_in, const int* in_sizes, int n_in,
                              void* d_out, int out_size, void* d_ws, size_t ws_size,
                              hipStream_t stream) {
  const float* x = (const float*)d_in[0];     // [8192][4096]
  const float* W = (const float*)d_in[1];     // [16384][4096]
  const float* bias = (const float*)d_in[2];  // [16384]
  float* out = (float*)d_out;

  const size_t nA = (size_t)M_DIM * K_DIM;
  const size_t nB = (size_t)N_DIM * K_DIM;
  const size_t need = (nA + nB) * sizeof(unsigned short);  // 192 MB

  if (ws_size >= need) {
    unsigned short* wsA = (unsigned short*)d_ws;
    unsigned short* wsB = wsA + nA;
    cvt_kernel<<<4096, 256, 0, stream>>>(x, wsA, (int)(nA / 4));
    cvt_kernel<<<4096, 256, 0, stream>>>(W, wsB, (int)(nB / 4));
    const int nblk = (M_DIM / 256) * (N_DIM / 256);  // 2048
    gemm8<<<nblk, 512, 131072, stream>>>((const short*)wsA, (const short*)wsB,
                                         bias, out);
  } else {
    const int nblk = (M_DIM / 128) * (N_DIM / 128);  // 8192
    gemm_f32<<<nblk, 256, 0, stream>>>(x, W, bias, out);
  }
}

// Round 3
// 1023.088 us; speedup vs baseline: 1.5725x; 1.0503x over previous
//
#include <hip/hip_runtime.h>
#include <hip/hip_bf16.h>

#define M_DIM 8192      // B*S = 4*2048
#define K_DIM 4096
#define N_DIM 16384

#define BK 64
#define NT (K_DIM / BK)   // 64 K-tiles

typedef __attribute__((ext_vector_type(8))) short bf16x8;
typedef __attribute__((ext_vector_type(4))) float f32x4;
typedef __attribute__((ext_vector_type(4))) unsigned short u16x4;

__device__ __forceinline__ unsigned short f2bf(float f) {
  unsigned int u = __builtin_bit_cast(unsigned int, f);
  u += 0x7fffu + ((u >> 16) & 1u);     // RNE
  return (unsigned short)(u >> 16);
}

// fp32 -> bf16, 4 elements/thread/iter, grid-stride.
// NT loads: source fp32 is read exactly once — don't cache it.
// Temporal stores: the bf16 ws is the GEMM's working set — want it in L3.
__global__ void cvt_kernel(const float* __restrict__ src,
                           unsigned short* __restrict__ dst, int n4) {
  int i = blockIdx.x * blockDim.x + threadIdx.x;
  int stride = gridDim.x * blockDim.x;
  for (; i < n4; i += stride) {
    f32x4 v = __builtin_nontemporal_load(&((const f32x4*)src)[i]);
    u16x4 o;
    o.x = f2bf(v.x); o.y = f2bf(v.y); o.z = f2bf(v.z); o.w = f2bf(v.w);
    ((u16x4*)dst)[i] = o;
  }
}

__device__ __forceinline__ void gload_lds16(const void* g, void* lds) {
  __builtin_amdgcn_global_load_lds(
      (const __attribute__((address_space(1))) unsigned int*)g,
      (__attribute__((address_space(3))) unsigned int*)lds, 16, 0, 0);
}

// ============================================================================
// 256x256 tile, BK=64, 8 waves (2M x 4N), 8-phase schedule w/ counted vmcnt.
// (sync structure identical to round 2 — verified; only block->tile mapping
//  and the C-store cache policy changed this round)
// LDS (128 KiB dynamic): lA = 4 slots [par][half] of 128x64 bf16 (16 KiB),
//                        lB = same at +64 KiB.
// Swizzle: phys 8-elem block = logical block ^ (row & 7)  (16B granularity).
// Staged with linear LDS dest + inverse-swizzled GLOBAL source (rule #21).
// Schedule per K-tile u (4 phases):
//   p0: read B frags (8 ds_read_b128) + A m0-1 (4) | stage Ah1(u+1)
//   p1: read A m2-3                                | stage Bh0(u+2)
//   p2: read A m4-5                                | stage Bh1(u+2)
//   p3: read A m6-7                                | stage Ah0(u+2) | vmcnt(6)
// ============================================================================
__global__ __launch_bounds__(512, 2) void gemm8(const short* __restrict__ A,
                                                const short* __restrict__ Bm,
                                                const float* __restrict__ bias,
                                                float* __restrict__ C) {
  extern __shared__ short lds[];
  short* lA = lds;           // 4 * 8192 shorts
  short* lB = lds + 32768;   // 4 * 8192 shorts

  const int tid = threadIdx.x;
  const int w = tid >> 6, l = tid & 63;
  const int wr = w >> 2;     // 0..1  (M half)
  const int wc = w & 3;      // 0..3  (N quarter)
  const int fr = l & 15;     // fragment row/col
  const int kq = l >> 4;     // k quarter
  const int sr = l >> 3;     // staging row-in-8
  const int sb = (l & 7) ^ sr;  // inverse-swizzled source block

  // ---- XCD-aware 2D tile mapping ----
  // 2048 blocks = 8 XCD chunks x 256 tiles. Chunk c covers bm in [4c,4c+4),
  // all 64 bn. Within-chunk order: (bno:8) x (bmi:4) x (bni:8), so the ~32
  // concurrently-resident blocks of an XCD form a 4bm x 8bn panel block:
  // per-K-step L2 window = (4+8) panels x 64KB = 768KB << 4MB L2, with each
  // B panel reused by 4 concurrent blocks and each A panel by 8.
  const int bid = blockIdx.x;
  const int chunk = bid & 7;        // XCD (dispatch round-robins bid % 8)
  const int local = bid >> 3;       // 0..255
  const int bno = local >> 5;       // 0..7
  const int rem = local & 31;
  const int bmi = rem >> 3;         // 0..3
  const int bni = rem & 7;          // 0..7
  const int bm = chunk * 4 + bmi;   // 0..31
  const int bn = bno * 8 + bni;     // 0..63
  const size_t m0 = (size_t)bm * 256, n0 = (size_t)bn * 256;

  const short* Abase = A + m0 * K_DIM;
  const short* Bbase = Bm + n0 * K_DIM;

  // stage one half-tile (128 rows x 64 elems) = 2 x gload_lds16 per thread
  auto stage = [&](short* lbase, const short* gbase, int slot, int half, int v) {
    const short* src = gbase + (size_t)(half * 128 + w * 8 + sr) * K_DIM +
                       (size_t)v * BK + sb * 8;
    short* dst = lbase + slot * 8192 + w * 512;
    gload_lds16(src, dst);                          // rows 0..63 of half
    gload_lds16(src + (size_t)64 * K_DIM, dst + 4096);  // rows 64..127
  };

  f32x4 acc[8][4];
#pragma unroll
  for (int mi = 0; mi < 8; ++mi)
#pragma unroll
    for (int ni = 0; ni < 4; ++ni) acc[mi][ni] = (f32x4){0.f, 0.f, 0.f, 0.f};

  float bv[4];
#pragma unroll
  for (int ni = 0; ni < 4; ++ni) bv[ni] = bias[n0 + wc * 64 + ni * 16 + fr];

  // ---- prologue: tile 0 complete + tile 1 {Bh0, Bh1, Ah0} ----
  stage(lB, Bbase, 0, 0, 0);
  stage(lB, Bbase, 1, 1, 0);
  stage(lA, Abase, 0, 0, 0);
  stage(lA, Abase, 1, 1, 0);
  stage(lB, Bbase, 2, 0, 1);
  stage(lB, Bbase, 3, 1, 1);
  stage(lA, Abase, 2, 0, 1);
  asm volatile("s_waitcnt vmcnt(6)");   // tile 0's 4 half-tiles landed
  __builtin_amdgcn_s_barrier();
  __builtin_amdgcn_sched_barrier(0);

  // ---- one K-tile group (4 phases); par is compile-time via call sites ----
  auto group = [&](const int par, const int u) {
    bf16x8 bfr[4][2];
#pragma unroll
    for (int p = 0; p < 4; ++p) {
      if (p == 0) {
#pragma unroll
        for (int ni = 0; ni < 4; ++ni) {
          int row = (wc & 1) * 64 + ni * 16 + fr;
          int base = (par * 2 + (wc >> 1)) * 8192 + row * 64;
          int x7 = (row & 7) << 3;
          bfr[ni][0] = *(const bf16x8*)&lB[base + ((kq * 8) ^ x7)];
          bfr[ni][1] = *(const bf16x8*)&lB[base + ((32 + kq * 8) ^ x7)];
        }
      }
      bf16x8 af[2][2];
#pragma unroll
      for (int i = 0; i < 2; ++i) {
        int row = (2 * p + i) * 16 + fr;
        int base = (par * 2 + wr) * 8192 + row * 64;
        int x7 = (row & 7) << 3;
        af[i][0] = *(const bf16x8*)&lA[base + ((kq * 8) ^ x7)];
        af[i][1] = *(const bf16x8*)&lA[base + ((32 + kq * 8) ^ x7)];
      }
      // staging per schedule
      if (p == 0) { if (u + 1 < NT) stage(lA, Abase, ((u + 1) & 1) * 2 + 1, 1, u + 1); }
      if (p == 1) { if (u + 2 < NT) stage(lB, Bbase, par * 2 + 0, 0, u + 2); }
      if (p == 2) { if (u + 2 < NT) stage(lB, Bbase, par * 2 + 1, 1, u + 2); }
      if (p == 3) { if (u + 2 < NT) stage(lA, Abase, par * 2 + 0, 0, u + 2); }

      if (p == 0) asm volatile("s_waitcnt lgkmcnt(8)");
      __builtin_amdgcn_sched_barrier(0);
      __builtin_amdgcn_s_barrier();
      asm volatile("s_waitcnt lgkmcnt(0)");
      __builtin_amdgcn_sched_barrier(0);
      __builtin_amdgcn_s_setprio(1);
#pragma unroll
      for (int i = 0; i < 2; ++i)
#pragma unroll
        for (int ni = 0; ni < 4; ++ni) {
          acc[2 * p + i][ni] = __builtin_amdgcn_mfma_f32_16x16x32_bf16(
              af[i][0], bfr[ni][0], acc[2 * p + i][ni], 0, 0, 0);
          acc[2 * p + i][ni] = __builtin_amdgcn_mfma_f32_16x16x32_bf16(
              af[i][1], bfr[ni][1], acc[2 * p + i][ni], 0, 0, 0);
        }
      __builtin_amdgcn_s_setprio(0);
      if (p == 3) {
        if (u < NT - 2) {
          asm volatile("s_waitcnt vmcnt(6)");   // next tile fully landed
        } else if (u == NT - 2) {
          asm volatile("s_waitcnt vmcnt(0)");   // drain for last tile
        }
      }
      __builtin_amdgcn_sched_barrier(0);
      __builtin_amdgcn_s_barrier();
      __builtin_amdgcn_sched_barrier(0);
    }
  };

  for (int t = 0; t < NT; t += 2) {
    group(0, t);
    group(1, t + 1);
  }

  // ---- epilogue: C/D layout col = lane&15, row = (lane>>4)*4 + reg ----
  // NT stores: C is write-once — keep the 512MB stream out of L2/L3 so the
  // bf16 operand set stays resident.
  const int crow0 = kq * 4;
#pragma unroll
  for (int mi = 0; mi < 8; ++mi) {
#pragma unroll
    for (int ni = 0; ni < 4; ++ni) {
      f32x4 v = acc[mi][ni];
      size_t col = n0 + wc * 64 + ni * 16 + fr;
      size_t rb = m0 + wr * 128 + mi * 16 + crow0;
#pragma unroll
      for (int j = 0; j < 4; ++j)
        __builtin_nontemporal_store(v[j] + bv[ni], &C[(rb + j) * N_DIM + col]);
    }
  }
}

// ---- fallback (ws too small): 128^2 kernel, fp32 in, reg-staged ----
__global__ __launch_bounds__(256) void gemm_f32(const float* __restrict__ Af,
                                                const float* __restrict__ Bf,
                                                const float* __restrict__ bias,
                                                float* __restrict__ C) {
  __shared__ short lA[128 * 64];
  __shared__ short lB[128 * 64];
  const int tid = threadIdx.x;
  const int w = tid >> 6, l = tid & 63;
  const int wr = w >> 1, wc = w & 1;
  int bid = blockIdx.x;
  int cpx = (M_DIM / 128) * (N_DIM / 128) / 8;
  int swz = (bid & 7) * cpx + (bid >> 3);
  const int bm = swz / (N_DIM / 128);
  const int bn = swz % (N_DIM / 128);
  const size_t m0 = (size_t)bm * 128, n0 = (size_t)bn * 128;
  const int lr = l >> 3, fr = l & 15, kq = l >> 4;

  f32x4 acc[4][4];
#pragma unroll
  for (int mi = 0; mi < 4; ++mi)
#pragma unroll
    for (int ni = 0; ni < 4; ++ni) acc[mi][ni] = (f32x4){0.f, 0.f, 0.f, 0.f};
  float bv[4];
#pragma unroll
  for (int ni = 0; ni < 4; ++ni) bv[ni] = bias[n0 + 64 * wc + 16 * ni + fr];

  for (int kt = 0; kt < K_DIM; kt += 64) {
    const float* Ab = Af + m0 * K_DIM + kt;
    const float* Bb = Bf + n0 * K_DIM + kt;
#pragma unroll
    for (int i = 0; i < 4; ++i) {
      int row = 32 * i + 8 * w + lr;
      int dsoff = row * 64 + ((8 * (l & 7)) ^ (lr << 3));
      f32x4 a0 = *(const f32x4*)(Ab + (size_t)row * K_DIM + 8 * (l & 7));
      f32x4 a1 = *(const f32x4*)(Ab + (size_t)row * K_DIM + 8 * (l & 7) + 4);
      bf16x8 ra;
#pragma unroll
      for (int j = 0; j < 4; ++j) { ra[j] = (short)f2bf(a0[j]); ra[j + 4] = (short)f2bf(a1[j]); }
      *(bf16x8*)&lA[dsoff] = ra;
      f32x4 b0 = *(const f32x4*)(Bb + (size_t)row * K_DIM + 8 * (l & 7));
      f32x4 b1 = *(const f32x4*)(Bb + (size_t)row * K_DIM + 8 * (l & 7) + 4);
      bf16x8 rb;
#pragma unroll
      for (int j = 0; j < 4; ++j) { rb[j] = (short)f2bf(b0[j]); rb[j + 4] = (short)f2bf(b1[j]); }
      *(bf16x8*)&lB[dsoff] = rb;
    }
    __syncthreads();
#pragma unroll
    for (int kk = 0; kk < 64; kk += 32) {
      bf16x8 af[4], bf_[4];
#pragma unroll
      for (int mi = 0; mi < 4; ++mi)
        af[mi] = *(const bf16x8*)&lA[(64 * wr + 16 * mi + fr) * 64 +
                                     ((kk + 8 * kq) ^ ((fr & 7) << 3))];
#pragma unroll
      for (int ni = 0; ni < 4; ++ni)
        bf_[ni] = *(const bf16x8*)&lB[(64 * wc + 16 * ni + fr) * 64 +
                                      ((kk + 8 * kq) ^ ((fr & 7) << 3))];
#pragma unroll
      for (int mi = 0; mi < 4; ++mi)
#pragma unroll
        for (int ni = 0; ni < 4; ++ni)
          acc[mi][ni] = __builtin_amdgcn_mfma_f32_16x16x32_bf16(
              af[mi], bf_[ni], acc[mi][ni], 0, 0, 0);
    }
    __syncthreads();
  }
  const int crow0 = kq * 4;
#pragma unroll
  for (int mi = 0; mi < 4; ++mi)
#pragma unroll
    for (int ni = 0; ni < 4; ++ni) {
      f32x4 v = acc[mi][ni];
      size_t col = n0 + 64 * wc + 16 * ni + fr;
      size_t rb = m0 + 64 * wr + 16 * mi + crow0;
#pragma unroll
      for (int j = 0; j < 4; ++j) C[(rb + j) * N_DIM + col] = v[j] + bv[ni];
    }
}

extern "C" void kernel_launch(void* const* d_in, const int* in_sizes, int n_in,
                              void* d_out, int out_size, void* d_ws, size_t ws_size,
                              hipStream_t stream) {
  const float* x = (const float*)d_in[0];     // [8192][4096]
  const float* W = (const float*)d_in[1];     // [16384][4096]
  const float* bias = (const float*)d_in[2];  // [16384]
  float* out = (float*)d_out;

  const size_t nA = (size_t)M_DIM * K_DIM;
  const size_t nB = (size_t)N_DIM * K_DIM;
  const size_t need = (nA + nB) * sizeof(unsigned short);  // 192 MB

  if (ws_size >= need) {
    unsigned short* wsA = (unsigned short*)d_ws;
    unsigned short* wsB = wsA + nA;
    cvt_kernel<<<4096, 256, 0, stream>>>(x, wsA, (int)(nA / 4));
    cvt_kernel<<<4096, 256, 0, stream>>>(W, wsB, (int)(nB / 4));
    const int nblk = (M_DIM / 256) * (N_DIM / 256);  // 2048
    gemm8<<<nblk, 512, 131072, stream>>>((const short*)wsA, (const short*)wsB,
                                         bias, out);
  } else {
    const int nblk = (M_DIM / 128) * (N_DIM / 128);  // 8192
    gemm_f32<<<nblk, 256, 0, stream>>>(x, W, bias, out);
  }
}

// Round 4
// 1008.452 us; speedup vs baseline: 1.5954x; 1.0145x over previous
//
#include <hip/hip_runtime.h>
#include <hip/hip_bf16.h>

#define M_DIM 8192      // B*S = 4*2048
#define K_DIM 4096
#define N_DIM 16384

#define BK 64
#define NT (K_DIM / BK)   // 64 K-tiles

typedef __attribute__((ext_vector_type(8))) short bf16x8;
typedef __attribute__((ext_vector_type(4))) float f32x4;
typedef __attribute__((ext_vector_type(4))) unsigned short u16x4;

__device__ __forceinline__ unsigned short f2bf(float f) {
  unsigned int u = __builtin_bit_cast(unsigned int, f);
  u += 0x7fffu + ((u >> 16) & 1u);     // RNE
  return (unsigned short)(u >> 16);
}

// fp32 -> bf16, 4 elements/thread/iter, grid-stride.
__global__ void cvt_kernel(const float* __restrict__ src,
                           unsigned short* __restrict__ dst, int n4) {
  int i = blockIdx.x * blockDim.x + threadIdx.x;
  int stride = gridDim.x * blockDim.x;
  for (; i < n4; i += stride) {
    f32x4 v = __builtin_nontemporal_load(&((const f32x4*)src)[i]);
    u16x4 o;
    o.x = f2bf(v.x); o.y = f2bf(v.y); o.z = f2bf(v.z); o.w = f2bf(v.w);
    ((u16x4*)dst)[i] = o;
  }
}

__device__ __forceinline__ void gload_lds16(const void* g, void* lds) {
  __builtin_amdgcn_global_load_lds(
      (const __attribute__((address_space(1))) unsigned int*)g,
      (__attribute__((address_space(3))) unsigned int*)lds, 16, 0, 0);
}

// ============================================================================
// 256x256 tile, BK=64, 8 waves (2M x 4N), 8-phase schedule, counted vmcnt.
// Round-4 changes vs round 3 (sync audit + latency-hiding):
//  (1) NO manual lgkmcnt pins: ds_reads are plain loads; the compiler emits
//      fine-grained lgkmcnt(N) before each first MFMA use, so MFMA overlaps
//      residual LDS read latency (round 3 pinned lgkmcnt(0) -> full latency
//      exposed between barriers -> MfmaUtil stuck at 51%).
//  (2) Strictly-sealed stage schedule (every stage targets a slot whose last
//      reader was sealed by a closing barrier BEFORE the stage issues):
//        p0: stage A(u+1)h0 -> slot (par^1)*2+0   [last read p3 of u-1]
//        p1: stage A(u+1)h1 -> slot (par^1)*2+1   [same]
//        p2: stage B(u+2)h0 -> slot  par  *2+0    [last read p0 of u]
//        p3: stage B(u+2)h1 -> slot  par  *2+1    [same]
//      Boundary: 6 stages (12 loads) outstanding, first 4 must land ->
//      s_waitcnt vmcnt(4), then barrier (all waves see landed data).
//  (3) Reads ordered first-consumed-first: af[0], bfr[0..3], af[1].
// LDS 128 KiB: lA = 4 slots of 128x64 bf16, lB same at +64 KiB.
// Swizzle: phys 8-elem block = logical ^ (row & 7); linear LDS dest +
// inverse-swizzled GLOBAL source (rule #21). 0 bank conflicts (measured).
// ============================================================================
__global__ __launch_bounds__(512, 2) void gemm8(const short* __restrict__ A,
                                                const short* __restrict__ Bm,
                                                const float* __restrict__ bias,
                                                float* __restrict__ C) {
  extern __shared__ short lds[];
  short* lA = lds;           // 4 * 8192 shorts
  short* lB = lds + 32768;   // 4 * 8192 shorts

  const int tid = threadIdx.x;
  const int w = tid >> 6, l = tid & 63;
  const int wr = w >> 2;     // 0..1  (M half)
  const int wc = w & 3;      // 0..3  (N quarter)
  const int fr = l & 15;     // fragment row/col
  const int kq = l >> 4;     // k quarter
  const int sr = l >> 3;     // staging row-in-8
  const int sb = (l & 7) ^ sr;  // inverse-swizzled source block

  // ---- XCD-aware 2D tile mapping (round 3, verified: FETCH 2.16->0.83 GB)
  const int bid = blockIdx.x;
  const int chunk = bid & 7;        // XCD
  const int local = bid >> 3;       // 0..255
  const int bno = local >> 5;       // 0..7
  const int rem = local & 31;
  const int bmi = rem >> 3;         // 0..3
  const int bni = rem & 7;          // 0..7
  const int bm = chunk * 4 + bmi;   // 0..31
  const int bn = bno * 8 + bni;     // 0..63
  const size_t m0 = (size_t)bm * 256, n0 = (size_t)bn * 256;

  const short* Abase = A + m0 * K_DIM;
  const short* Bbase = Bm + n0 * K_DIM;

  // stage one half-tile (128 rows x 64 elems) = 2 x gload_lds16 per thread
  auto stage = [&](short* lbase, const short* gbase, int slot, int half, int v) {
    const short* src = gbase + (size_t)(half * 128 + w * 8 + sr) * K_DIM +
                       (size_t)v * BK + sb * 8;
    short* dst = lbase + slot * 8192 + w * 512;
    gload_lds16(src, dst);                          // rows 0..63 of half
    gload_lds16(src + (size_t)64 * K_DIM, dst + 4096);  // rows 64..127
  };

  f32x4 acc[8][4];
#pragma unroll
  for (int mi = 0; mi < 8; ++mi)
#pragma unroll
    for (int ni = 0; ni < 4; ++ni) acc[mi][ni] = (f32x4){0.f, 0.f, 0.f, 0.f};

  float bv[4];
#pragma unroll
  for (int ni = 0; ni < 4; ++ni) bv[ni] = bias[n0 + wc * 64 + ni * 16 + fr];

  // ---- prologue: tile0 {B,A} + tile1 {B}; A(1) staged at p0/p1 of group 0 --
  stage(lB, Bbase, 0, 0, 0);
  stage(lB, Bbase, 1, 1, 0);
  stage(lA, Abase, 0, 0, 0);
  stage(lA, Abase, 1, 1, 0);
  stage(lB, Bbase, 2, 0, 1);
  stage(lB, Bbase, 3, 1, 1);
  asm volatile("s_waitcnt vmcnt(4)");   // tile 0's 4 stages landed
  __builtin_amdgcn_s_barrier();
  __builtin_amdgcn_sched_barrier(0);

  // ---- one K-tile group (4 phases); par compile-time via call sites ----
  auto group = [&](const int par, const int u) {
    bf16x8 bfr[4][2];
#pragma unroll
    for (int p = 0; p < 4; ++p) {
      // staging (strictly sealed; see header)
      if (p == 0) { if (u + 1 < NT) stage(lA, Abase, ((par ^ 1) << 1) + 0, 0, u + 1); }
      if (p == 1) { if (u + 1 < NT) stage(lA, Abase, ((par ^ 1) << 1) + 1, 1, u + 1); }
      if (p == 2) { if (u + 2 < NT) stage(lB, Bbase, (par << 1) + 0, 0, u + 2); }
      if (p == 3) { if (u + 2 < NT) stage(lB, Bbase, (par << 1) + 1, 1, u + 2); }

      // ds reads, first-consumed-first; compiler schedules the lgkm waits
      bf16x8 af[2][2];
      {
        int row = (2 * p + 0) * 16 + fr;
        int base = (par * 2 + wr) * 8192 + row * 64;
        int x7 = (row & 7) << 3;
        af[0][0] = *(const bf16x8*)&lA[base + ((kq * 8) ^ x7)];
        af[0][1] = *(const bf16x8*)&lA[base + ((32 + kq * 8) ^ x7)];
      }
      if (p == 0) {
#pragma unroll
        for (int ni = 0; ni < 4; ++ni) {
          int row = (wc & 1) * 64 + ni * 16 + fr;
          int base = (par * 2 + (wc >> 1)) * 8192 + row * 64;
          int x7 = (row & 7) << 3;
          bfr[ni][0] = *(const bf16x8*)&lB[base + ((kq * 8) ^ x7)];
          bfr[ni][1] = *(const bf16x8*)&lB[base + ((32 + kq * 8) ^ x7)];
        }
      }
      {
        int row = (2 * p + 1) * 16 + fr;
        int base = (par * 2 + wr) * 8192 + row * 64;
        int x7 = (row & 7) << 3;
        af[1][0] = *(const bf16x8*)&lA[base + ((kq * 8) ^ x7)];
        af[1][1] = *(const bf16x8*)&lA[base + ((32 + kq * 8) ^ x7)];
      }

      __builtin_amdgcn_s_barrier();
      __builtin_amdgcn_s_setprio(1);
#pragma unroll
      for (int i = 0; i < 2; ++i)
#pragma unroll
        for (int ni = 0; ni < 4; ++ni) {
          acc[2 * p + i][ni] = __builtin_amdgcn_mfma_f32_16x16x32_bf16(
              af[i][0], bfr[ni][0], acc[2 * p + i][ni], 0, 0, 0);
          acc[2 * p + i][ni] = __builtin_amdgcn_mfma_f32_16x16x32_bf16(
              af[i][1], bfr[ni][1], acc[2 * p + i][ni], 0, 0, 0);
        }
      __builtin_amdgcn_s_setprio(0);
      if (p == 3) {
        __builtin_amdgcn_sched_barrier(0);
        if (u < NT - 2) {
          asm volatile("s_waitcnt vmcnt(4)");   // next tile fully landed
        } else if (u == NT - 2) {
          asm volatile("s_waitcnt vmcnt(0)");   // drain for last tile
        }
        __builtin_amdgcn_sched_barrier(0);
      }
      __builtin_amdgcn_s_barrier();
    }
  };

  for (int t = 0; t < NT; t += 2) {
    group(0, t);
    group(1, t + 1);
  }

  // ---- epilogue: C/D layout col = lane&15, row = (lane>>4)*4 + reg ----
  const int crow0 = kq * 4;
#pragma unroll
  for (int mi = 0; mi < 8; ++mi) {
#pragma unroll
    for (int ni = 0; ni < 4; ++ni) {
      f32x4 v = acc[mi][ni];
      size_t col = n0 + wc * 64 + ni * 16 + fr;
      size_t rb = m0 + wr * 128 + mi * 16 + crow0;
#pragma unroll
      for (int j = 0; j < 4; ++j)
        __builtin_nontemporal_store(v[j] + bv[ni], &C[(rb + j) * N_DIM + col]);
    }
  }
}

// ---- fallback (ws too small): 128^2 kernel, fp32 in, reg-staged ----
__global__ __launch_bounds__(256) void gemm_f32(const float* __restrict__ Af,
                                                const float* __restrict__ Bf,
                                                const float* __restrict__ bias,
                                                float* __restrict__ C) {
  __shared__ short lA[128 * 64];
  __shared__ short lB[128 * 64];
  const int tid = threadIdx.x;
  const int w = tid >> 6, l = tid & 63;
  const int wr = w >> 1, wc = w & 1;
  int bid = blockIdx.x;
  int cpx = (M_DIM / 128) * (N_DIM / 128) / 8;
  int swz = (bid & 7) * cpx + (bid >> 3);
  const int bm = swz / (N_DIM / 128);
  const int bn = swz % (N_DIM / 128);
  const size_t m0 = (size_t)bm * 128, n0 = (size_t)bn * 128;
  const int lr = l >> 3, fr = l & 15, kq = l >> 4;

  f32x4 acc[4][4];
#pragma unroll
  for (int mi = 0; mi < 4; ++mi)
#pragma unroll
    for (int ni = 0; ni < 4; ++ni) acc[mi][ni] = (f32x4){0.f, 0.f, 0.f, 0.f};
  float bv[4];
#pragma unroll
  for (int ni = 0; ni < 4; ++ni) bv[ni] = bias[n0 + 64 * wc + 16 * ni + fr];

  for (int kt = 0; kt < K_DIM; kt += 64) {
    const float* Ab = Af + m0 * K_DIM + kt;
    const float* Bb = Bf + n0 * K_DIM + kt;
#pragma unroll
    for (int i = 0; i < 4; ++i) {
      int row = 32 * i + 8 * w + lr;
      int dsoff = row * 64 + ((8 * (l & 7)) ^ (lr << 3));
      f32x4 a0 = *(const f32x4*)(Ab + (size_t)row * K_DIM + 8 * (l & 7));
      f32x4 a1 = *(const f32x4*)(Ab + (size_t)row * K_DIM + 8 * (l & 7) + 4);
      bf16x8 ra;
#pragma unroll
      for (int j = 0; j < 4; ++j) { ra[j] = (short)f2bf(a0[j]); ra[j + 4] = (short)f2bf(a1[j]); }
      *(bf16x8*)&lA[dsoff] = ra;
      f32x4 b0 = *(const f32x4*)(Bb + (size_t)row * K_DIM + 8 * (l & 7));
      f32x4 b1 = *(const f32x4*)(Bb + (size_t)row * K_DIM + 8 * (l & 7) + 4);
      bf16x8 rb;
#pragma unroll
      for (int j = 0; j < 4; ++j) { rb[j] = (short)f2bf(b0[j]); rb[j + 4] = (short)f2bf(b1[j]); }
      *(bf16x8*)&lB[dsoff] = rb;
    }
    __syncthreads();
#pragma unroll
    for (int kk = 0; kk < 64; kk += 32) {
      bf16x8 af[4], bf_[4];
#pragma unroll
      for (int mi = 0; mi < 4; ++mi)
        af[mi] = *(const bf16x8*)&lA[(64 * wr + 16 * mi + fr) * 64 +
                                     ((kk + 8 * kq) ^ ((fr & 7) << 3))];
#pragma unroll
      for (int ni = 0; ni < 4; ++ni)
        bf_[ni] = *(const bf16x8*)&lB[(64 * wc + 16 * ni + fr) * 64 +
                                      ((kk + 8 * kq) ^ ((fr & 7) << 3))];
#pragma unroll
      for (int mi = 0; mi < 4; ++mi)
#pragma unroll
        for (int ni = 0; ni < 4; ++ni)
          acc[mi][ni] = __builtin_amdgcn_mfma_f32_16x16x32_bf16(
              af[mi], bf_[ni], acc[mi][ni], 0, 0, 0);
    }
    __syncthreads();
  }
  const int crow0 = kq * 4;
#pragma unroll
  for (int mi = 0; mi < 4; ++mi)
#pragma unroll
    for (int ni = 0; ni < 4; ++ni) {
      f32x4 v = acc[mi][ni];
      size_t col = n0 + 64 * wc + 16 * ni + fr;
      size_t rb = m0 + 64 * wr + 16 * mi + crow0;
#pragma unroll
      for (int j = 0; j < 4; ++j) C[(rb + j) * N_DIM + col] = v[j] + bv[ni];
    }
}

extern "C" void kernel_launch(void* const* d_in, const int* in_sizes, int n_in,
                              void* d_out, int out_size, void* d_ws, size_t ws_size,
                              hipStream_t stream) {
  const float* x = (const float*)d_in[0];     // [8192][4096]
  const float* W = (const float*)d_in[1];     // [16384][4096]
  const float* bias = (const float*)d_in[2];  // [16384]
  float* out = (float*)d_out;

  const size_t nA = (size_t)M_DIM * K_DIM;
  const size_t nB = (size_t)N_DIM * K_DIM;
  const size_t need = (nA + nB) * sizeof(unsigned short);  // 192 MB

  if (ws_size >= need) {
    unsigned short* wsA = (unsigned short*)d_ws;
    unsigned short* wsB = wsA + nA;
    cvt_kernel<<<4096, 256, 0, stream>>>(x, wsA, (int)(nA / 4));
    cvt_kernel<<<4096, 256, 0, stream>>>(W, wsB, (int)(nB / 4));
    const int nblk = (M_DIM / 256) * (N_DIM / 256);  // 2048
    gemm8<<<nblk, 512, 131072, stream>>>((const short*)wsA, (const short*)wsB,
                                         bias, out);
  } else {
    const int nblk = (M_DIM / 128) * (N_DIM / 128);  // 8192
    gemm_f32<<<nblk, 256, 0, stream>>>(x, W, bias, out);
  }
}

// Round 5
// 996.723 us; speedup vs baseline: 1.6141x; 1.0118x over previous
//
#include <hip/hip_runtime.h>
#include <hip/hip_bf16.h>

#define M_DIM 8192      // B*S = 4*2048
#define K_DIM 4096
#define N_DIM 16384

#define BK 64
#define NT (K_DIM / BK)   // 64 K-tiles

typedef __attribute__((ext_vector_type(8))) short bf16x8;
typedef __attribute__((ext_vector_type(4))) float f32x4;
typedef __attribute__((ext_vector_type(4))) unsigned short u16x4;

__device__ __forceinline__ unsigned short f2bf(float f) {
  unsigned int u = __builtin_bit_cast(unsigned int, f);
  u += 0x7fffu + ((u >> 16) & 1u);     // RNE
  return (unsigned short)(u >> 16);
}

// fp32 -> bf16, 4 elements/thread/iter, grid-stride.
__global__ void cvt_kernel(const float* __restrict__ src,
                           unsigned short* __restrict__ dst, int n4) {
  int i = blockIdx.x * blockDim.x + threadIdx.x;
  int stride = gridDim.x * blockDim.x;
  for (; i < n4; i += stride) {
    f32x4 v = __builtin_nontemporal_load(&((const f32x4*)src)[i]);
    u16x4 o;
    o.x = f2bf(v.x); o.y = f2bf(v.y); o.z = f2bf(v.z); o.w = f2bf(v.w);
    ((u16x4*)dst)[i] = o;
  }
}

__device__ __forceinline__ void gload_lds16(const void* g, void* lds) {
  __builtin_amdgcn_global_load_lds(
      (const __attribute__((address_space(1))) unsigned int*)g,
      (__attribute__((address_space(3))) unsigned int*)lds, 16, 0, 0);
}

// ============================================================================
// PERSISTENT 256-block version. Each block owns one CU (LDS=160KB forces
// 1 block/CU), fixed bm = (p&7)*4 + (p>>6... see decode), sweeps 8 bn tiles.
// Per tile: the verified round-4 K-loop body (8-phase, counted vmcnt,
// sealed stage schedule — UNCHANGED). New tile-boundary flow:
//   [K-loop, ends fully drained (vmcnt(0) at u==NT-2)]
//   [issue next tile's 6 prologue stages (12 gloads) — latency hides below]
//   [epilogue: acc -> 32KB wave-private LDS bounce -> dwordx4 nt stores]
//   top of next iter: s_waitcnt vmcnt(36) = (12 gloads + 32 stores
//     outstanding, in-order retirement) -> oldest 8 gloads (B0+A0) landed;
//     equivalent to the old prologue vmcnt(4). r==0 uses vmcnt(4) directly.
// LDS map (163840 B): lA 64KB @0 | lB 64KB @64K | epilogue bounce 32KB @128K
// (8 waves x 4KB: wave-private, no barriers needed in epilogue).
// ============================================================================
__global__ __launch_bounds__(512, 2) void gemm8p(const short* __restrict__ A,
                                                 const short* __restrict__ Bm,
                                                 const float* __restrict__ bias,
                                                 float* __restrict__ C) {
  extern __shared__ short lds[];
  short* lA = lds;                     // 4 slots * 8192 shorts
  short* lB = lds + 32768;             // 4 slots * 8192 shorts
  float* ep = (float*)(lds + 65536);   // 32 KB bounce

  const int tid = threadIdx.x;
  const int w = tid >> 6, l = tid & 63;
  const int wr = w >> 2;     // 0..1  (M half)
  const int wc = w & 3;      // 0..3  (N quarter)
  const int fr = l & 15;     // fragment row/col
  const int kq = l >> 4;     // k quarter
  const int sr = l >> 3;     // staging row-in-8
  const int sb = (l & 7) ^ sr;  // inverse-swizzled source block

  // ---- persistent tile assignment: fixed bm per block, bn sweeps 8 ----
  const int p = blockIdx.x;          // 0..255
  const int xcd = p & 7;
  const int slot = p >> 3;           // 0..31
  const int bm = xcd * 4 + (slot >> 3);  // 0..31 (A panel pinned per CU)
  const int bni = slot & 7;
  const size_t m0 = (size_t)bm * 256;
  const short* Abase = A + m0 * K_DIM;
  float* epw = ep + w * 1024;        // wave-private 4 KB (16 rows x 64 f32)

  // stage one half-tile (128 rows x 64 elems) = 2 x gload_lds16 per thread
  auto stage = [&](short* lbase, const short* gbase, int slotn, int half, int v) {
    const short* src = gbase + (size_t)(half * 128 + w * 8 + sr) * K_DIM +
                       (size_t)v * BK + sb * 8;
    short* dst = lbase + slotn * 8192 + w * 512;
    gload_lds16(src, dst);                          // rows 0..63 of half
    gload_lds16(src + (size_t)64 * K_DIM, dst + 4096);  // rows 64..127
  };

#pragma unroll 1
  for (int r = 0; r < 8; ++r) {
    const int bn = r * 8 + bni;        // 0..63
    const size_t n0 = (size_t)bn * 256;
    const short* Bbase = Bm + n0 * K_DIM;

    f32x4 acc[8][4];
#pragma unroll
    for (int mi = 0; mi < 8; ++mi)
#pragma unroll
      for (int ni = 0; ni < 4; ++ni) acc[mi][ni] = (f32x4){0.f, 0.f, 0.f, 0.f};

    if (r == 0) {
      // cold prologue: tile0 {B,A} + tile1 {B}
      stage(lB, Bbase, 0, 0, 0);
      stage(lB, Bbase, 1, 1, 0);
      stage(lA, Abase, 0, 0, 0);
      stage(lA, Abase, 1, 1, 0);
      stage(lB, Bbase, 2, 0, 1);
      stage(lB, Bbase, 3, 1, 1);
      asm volatile("s_waitcnt vmcnt(4)");   // first 8 gloads (B0+A0) landed
    } else {
      // warm prologue: 12 gloads + 32 stores outstanding (issued in that
      // order last iter); in-order retirement -> <=36 left == oldest 8
      // gloads (B0+A0) landed.
      asm volatile("s_waitcnt vmcnt(36)");
    }
    __builtin_amdgcn_s_barrier();
    __builtin_amdgcn_sched_barrier(0);

    // ---- one K-tile group (4 phases); body identical to round 4 ----
    auto group = [&](const int par, const int u) {
      bf16x8 bfr[4][2];
#pragma unroll
      for (int ph = 0; ph < 4; ++ph) {
        // staging (strictly sealed)
        if (ph == 0) { if (u + 1 < NT) stage(lA, Abase, ((par ^ 1) << 1) + 0, 0, u + 1); }
        if (ph == 1) { if (u + 1 < NT) stage(lA, Abase, ((par ^ 1) << 1) + 1, 1, u + 1); }
        if (ph == 2) { if (u + 2 < NT) stage(lB, Bbase, (par << 1) + 0, 0, u + 2); }
        if (ph == 3) { if (u + 2 < NT) stage(lB, Bbase, (par << 1) + 1, 1, u + 2); }

        // ds reads, first-consumed-first; compiler schedules lgkm waits
        bf16x8 af[2][2];
        {
          int row = (2 * ph + 0) * 16 + fr;
          int base = (par * 2 + wr) * 8192 + row * 64;
          int x7 = (row & 7) << 3;
          af[0][0] = *(const bf16x8*)&lA[base + ((kq * 8) ^ x7)];
          af[0][1] = *(const bf16x8*)&lA[base + ((32 + kq * 8) ^ x7)];
        }
        if (ph == 0) {
#pragma unroll
          for (int ni = 0; ni < 4; ++ni) {
            int row = (wc & 1) * 64 + ni * 16 + fr;
            int base = (par * 2 + (wc >> 1)) * 8192 + row * 64;
            int x7 = (row & 7) << 3;
            bfr[ni][0] = *(const bf16x8*)&lB[base + ((kq * 8) ^ x7)];
            bfr[ni][1] = *(const bf16x8*)&lB[base + ((32 + kq * 8) ^ x7)];
          }
        }
        {
          int row = (2 * ph + 1) * 16 + fr;
          int base = (par * 2 + wr) * 8192 + row * 64;
          int x7 = (row & 7) << 3;
          af[1][0] = *(const bf16x8*)&lA[base + ((kq * 8) ^ x7)];
          af[1][1] = *(const bf16x8*)&lA[base + ((32 + kq * 8) ^ x7)];
        }

        __builtin_amdgcn_s_barrier();
        __builtin_amdgcn_s_setprio(1);
#pragma unroll
        for (int i = 0; i < 2; ++i)
#pragma unroll
          for (int ni = 0; ni < 4; ++ni) {
            acc[2 * ph + i][ni] = __builtin_amdgcn_mfma_f32_16x16x32_bf16(
                af[i][0], bfr[ni][0], acc[2 * ph + i][ni], 0, 0, 0);
            acc[2 * ph + i][ni] = __builtin_amdgcn_mfma_f32_16x16x32_bf16(
                af[i][1], bfr[ni][1], acc[2 * ph + i][ni], 0, 0, 0);
          }
        __builtin_amdgcn_s_setprio(0);
        if (ph == 3) {
          __builtin_amdgcn_sched_barrier(0);
          if (u < NT - 2) {
            asm volatile("s_waitcnt vmcnt(4)");   // next tile fully landed
          } else if (u == NT - 2) {
            asm volatile("s_waitcnt vmcnt(0)");   // drain for last tile
          }
          __builtin_amdgcn_sched_barrier(0);
        }
        __builtin_amdgcn_s_barrier();
      }
    };

    for (int t = 0; t < NT; t += 2) {
      group(0, t);
      group(1, t + 1);
    }
    // here: all vmem drained (vmcnt(0) at u==NT-2), all LDS slots dead.

    // ---- issue next tile's prologue BEFORE epilogue (latency hides) ----
    if (r + 1 < 8) {
      const short* Bb2 = Bm + (size_t)(bn + 8) * 256 * K_DIM;
      stage(lB, Bb2, 0, 0, 0);
      stage(lB, Bb2, 1, 1, 0);
      stage(lA, Abase, 0, 0, 0);
      stage(lA, Abase, 1, 1, 0);
      stage(lB, Bb2, 2, 0, 1);
      stage(lB, Bb2, 3, 1, 1);
    }

    // ---- epilogue: transpose via wave-private LDS, 256B-segment stores ---
    // acc lane layout: col = ni*16+fr, rows = kq*4 + j (per mi block of 16).
    // Bounce to epw[16][64] then read row-contiguous float4 per lane.
    f32x4 bias4 = *(const f32x4*)&bias[n0 + wc * 64 + fr * 4];
#pragma unroll
    for (int mi = 0; mi < 8; ++mi) {
#pragma unroll
      for (int ni = 0; ni < 4; ++ni)
#pragma unroll
        for (int j = 0; j < 4; ++j)
          epw[(kq * 4 + j) * 64 + ni * 16 + fr] = acc[mi][ni][j];
      // same-wave DS ops retire in order; reads below see the writes
#pragma unroll
      for (int ps = 0; ps < 4; ++ps) {
        int row = ps * 4 + kq;           // 0..15
        f32x4 v = *(const f32x4*)&epw[row * 64 + fr * 4];
        v += bias4;
        size_t grow = m0 + (size_t)wr * 128 + mi * 16 + row;
        __builtin_nontemporal_store(
            v, (f32x4*)&C[grow * N_DIM + n0 + wc * 64 + fr * 4]);
      }
    }
  }
}

// ---- fallback (ws too small): 128^2 kernel, fp32 in, reg-staged ----
__global__ __launch_bounds__(256) void gemm_f32(const float* __restrict__ Af,
                                                const float* __restrict__ Bf,
                                                const float* __restrict__ bias,
                                                float* __restrict__ C) {
  __shared__ short lA[128 * 64];
  __shared__ short lB[128 * 64];
  const int tid = threadIdx.x;
  const int w = tid >> 6, l = tid & 63;
  const int wr = w >> 1, wc = w & 1;
  int bid = blockIdx.x;
  int cpx = (M_DIM / 128) * (N_DIM / 128) / 8;
  int swz = (bid & 7) * cpx + (bid >> 3);
  const int bm = swz / (N_DIM / 128);
  const int bn = swz % (N_DIM / 128);
  const size_t m0 = (size_t)bm * 128, n0 = (size_t)bn * 128;
  const int lr = l >> 3, fr = l & 15, kq = l >> 4;

  f32x4 acc[4][4];
#pragma unroll
  for (int mi = 0; mi < 4; ++mi)
#pragma unroll
    for (int ni = 0; ni < 4; ++ni) acc[mi][ni] = (f32x4){0.f, 0.f, 0.f, 0.f};
  float bv[4];
#pragma unroll
  for (int ni = 0; ni < 4; ++ni) bv[ni] = bias[n0 + 64 * wc + 16 * ni + fr];

  for (int kt = 0; kt < K_DIM; kt += 64) {
    const float* Ab = Af + m0 * K_DIM + kt;
    const float* Bb = Bf + n0 * K_DIM + kt;
#pragma unroll
    for (int i = 0; i < 4; ++i) {
      int row = 32 * i + 8 * w + lr;
      int dsoff = row * 64 + ((8 * (l & 7)) ^ (lr << 3));
      f32x4 a0 = *(const f32x4*)(Ab + (size_t)row * K_DIM + 8 * (l & 7));
      f32x4 a1 = *(const f32x4*)(Ab + (size_t)row * K_DIM + 8 * (l & 7) + 4);
      bf16x8 ra;
#pragma unroll
      for (int j = 0; j < 4; ++j) { ra[j] = (short)f2bf(a0[j]); ra[j + 4] = (short)f2bf(a1[j]); }
      *(bf16x8*)&lA[dsoff] = ra;
      f32x4 b0 = *(const f32x4*)(Bb + (size_t)row * K_DIM + 8 * (l & 7));
      f32x4 b1 = *(const f32x4*)(Bb + (size_t)row * K_DIM + 8 * (l & 7) + 4);
      bf16x8 rb;
#pragma unroll
      for (int j = 0; j < 4; ++j) { rb[j] = (short)f2bf(b0[j]); rb[j + 4] = (short)f2bf(b1[j]); }
      *(bf16x8*)&lB[dsoff] = rb;
    }
    __syncthreads();
#pragma unroll
    for (int kk = 0; kk < 64; kk += 32) {
      bf16x8 af[4], bf_[4];
#pragma unroll
      for (int mi = 0; mi < 4; ++mi)
        af[mi] = *(const bf16x8*)&lA[(64 * wr + 16 * mi + fr) * 64 +
                                     ((kk + 8 * kq) ^ ((fr & 7) << 3))];
#pragma unroll
      for (int ni = 0; ni < 4; ++ni)
        bf_[ni] = *(const bf16x8*)&lB[(64 * wc + 16 * ni + fr) * 64 +
                                      ((kk + 8 * kq) ^ ((fr & 7) << 3))];
#pragma unroll
      for (int mi = 0; mi < 4; ++mi)
#pragma unroll
        for (int ni = 0; ni < 4; ++ni)
          acc[mi][ni] = __builtin_amdgcn_mfma_f32_16x16x32_bf16(
              af[mi], bf_[ni], acc[mi][ni], 0, 0, 0);
    }
    __syncthreads();
  }
  const int crow0 = kq * 4;
#pragma unroll
  for (int mi = 0; mi < 4; ++mi)
#pragma unroll
    for (int ni = 0; ni < 4; ++ni) {
      f32x4 v = acc[mi][ni];
      size_t col = n0 + 64 * wc + 16 * ni + fr;
      size_t rb = m0 + 64 * wr + 16 * mi + crow0;
#pragma unroll
      for (int j = 0; j < 4; ++j) C[(rb + j) * N_DIM + col] = v[j] + bv[ni];
    }
}

extern "C" void kernel_launch(void* const* d_in, const int* in_sizes, int n_in,
                              void* d_out, int out_size, void* d_ws, size_t ws_size,
                              hipStream_t stream) {
  const float* x = (const float*)d_in[0];     // [8192][4096]
  const float* W = (const float*)d_in[1];     // [16384][4096]
  const float* bias = (const float*)d_in[2];  // [16384]
  float* out = (float*)d_out;

  const size_t nA = (size_t)M_DIM * K_DIM;
  const size_t nB = (size_t)N_DIM * K_DIM;
  const size_t need = (nA + nB) * sizeof(unsigned short);  // 192 MB

  if (ws_size >= need) {
    unsigned short* wsA = (unsigned short*)d_ws;
    unsigned short* wsB = wsA + nA;
    // allow 160 KB dynamic LDS (no-op if already permitted)
    hipFuncSetAttribute((const void*)gemm8p,
                        hipFuncAttributeMaxDynamicSharedMemorySize, 163840);
    cvt_kernel<<<4096, 256, 0, stream>>>(x, wsA, (int)(nA / 4));
    cvt_kernel<<<4096, 256, 0, stream>>>(W, wsB, (int)(nB / 4));
    gemm8p<<<256, 512, 163840, stream>>>((const short*)wsA, (const short*)wsB,
                                         bias, out);
  } else {
    const int nblk = (M_DIM / 128) * (N_DIM / 128);  // 8192
    gemm_f32<<<nblk, 256, 0, stream>>>(x, W, bias, out);
  }
}